// Round 10
// baseline (690.719 us; speedup 1.0000x reference)
//
#include <hip/hip_runtime.h>

#define NB 4
#define NS 8192
#define NE 1024
#define NH 16
#define ND 64
#define NM (NB*NS)          // 32768 rows
#define NKT 16              // K-tiles of 64 in NE=1024

typedef __bf16 bf16x8 __attribute__((ext_vector_type(8)));
typedef float  f32x4  __attribute__((ext_vector_type(4)));
typedef unsigned short u16x8 __attribute__((ext_vector_type(8)));

__device__ __forceinline__ unsigned short f2bf(float f){
  unsigned int u = __float_as_uint(f);
  u += 0x7FFFu + ((u >> 16) & 1u);
  return (unsigned short)(u >> 16);
}
__device__ __forceinline__ float bf2f(unsigned short h){
  return __uint_as_float(((unsigned int)h) << 16);
}
__device__ __forceinline__ void gload16(const void* g, void* lds){
  __builtin_amdgcn_global_load_lds(
      (__attribute__((address_space(1))) unsigned int*)g,
      (__attribute__((address_space(3))) unsigned int*)lds, 16, 0, 0);
}

// ---- mask canonicalization: detect int32 vs byte layout on-device ----
__global__ void mask_prep(const void* mraw, unsigned char* mask_u8){
  __shared__ int flag_s;
  if (threadIdx.x == 0) flag_s = 0;
  __syncthreads();
  const unsigned int* mi = (const unsigned int*)mraw;
  int bad = 0;
  for (int i = threadIdx.x; i < 4096; i += 256) bad |= (mi[i] > 1u) ? 1 : 0;
  if (bad) atomicOr(&flag_s, 1);
  __syncthreads();
  const int isbyte = flag_s;
  const unsigned char* mb = (const unsigned char*)mraw;
  int stride = gridDim.x * blockDim.x;
  for (int i = blockIdx.x*blockDim.x + threadIdx.x; i < NM; i += stride)
    mask_u8[i] = isbyte ? (unsigned char)(mb[i] != 0) : (unsigned char)(mi[i] != 0);
}

// ---- f32 -> bf16 cast ----
struct CastJobs {
  const float* src[5];
  unsigned short* dst[5];
  int n4[5];
};

__global__ __launch_bounds__(256) void castk(CastJobs J){
  int j = blockIdx.y;
  const float* s = J.src[j];
  unsigned short* d = J.dst[j];
  int n4 = J.n4[j];
  int stride = gridDim.x * blockDim.x;
  for (int i = blockIdx.x*blockDim.x + threadIdx.x; i < n4; i += stride){
    float4 v = *(const float4*)(s + (long)i*4);
    ushort4 o;
    o.x = f2bf(v.x); o.y = f2bf(v.y); o.z = f2bf(v.z); o.w = f2bf(v.w);
    *(ushort4*)(d + (long)i*4) = o;
  }
}

// ============ 256x256 bf16 GEMM: 2-sync K-tile, full-tile reg residency ============
// mode 1: bf16, elu+1+mask (K) | 2: bf16, mask (V) | 3: f32 out, plain (@Wo^T)
__global__ __launch_bounds__(512, 2) void gemm256(
    const unsigned short* __restrict__ A,
    const unsigned short* __restrict__ W1,
    const unsigned short* __restrict__ W2,
    unsigned short* __restrict__ O1,
    unsigned short* __restrict__ O2,
    float* __restrict__ OF,
    const unsigned char* __restrict__ mask,
    int modeSel)
{
  __shared__ __align__(16) unsigned short As[2*256*64];
  __shared__ __align__(16) unsigned short Bs[2*256*64];

  const int mode = (modeSel < 0) ? (int)blockIdx.y + 1 : modeSel;
  const unsigned short* Bw = (mode==1) ? W1 : (mode==2) ? W2 : W1;
  unsigned short* Obf = (mode==1) ? O1 : O2;

  const int nwg = (int)gridDim.x;
  const int bx  = (int)blockIdx.x;
  const int swz = (bx & 7) * (nwg >> 3) + (bx >> 3);
  const long m0 = (long)(swz >> 2) * 256;
  const int  n0 = (swz & 3) * 256;

  const int tid = (int)threadIdx.x;
  const int l   = tid & 63;
  const int wv  = tid >> 6;
  const int wr  = wv >> 2;
  const int wc  = wv & 3;
  const int l15 = l & 15;
  const int lhi = l >> 4;
  const int swz8 = (l & 7) * 8;

  const int srow = wv*16 + (l >> 3);
  const int scol = ((l & 7) * 8) ^ ((l >> 3) << 3);

  auto stageA = [&](int st, int h){
    if (st >= NKT) return;
    const long col = (long)st*64 + scol;
    #pragma unroll
    for (int is = 0; is < 2; ++is)
      gload16(A + (m0 + h*128 + srow + is*8)*NE + col,
              &As[(st & 1)*16384 + h*8192 + (wv*2 + is)*512]);
  };
  auto stageB = [&](int st, int h){
    if (st >= NKT) return;
    const long col = (long)st*64 + scol;
    #pragma unroll
    for (int is = 0; is < 2; ++is)
      gload16(Bw + (long)(n0 + h*128 + srow + is*8)*NE + col,
              &Bs[(st & 1)*16384 + h*8192 + (wv*2 + is)*512]);
  };

  auto lda = [&](int buf, int mi, int ks)->bf16x8 {
    const int row = wr*128 + mi*16 + l15;
    const int col = (ks*32 + lhi*8) ^ swz8;
    return *(const bf16x8*)&As[buf*16384 + row*64 + col];
  };
  auto ldb = [&](int buf, int ni, int ks)->bf16x8 {
    const int row = wc*64 + ni*16 + l15;
    const int col = (ks*32 + lhi*8) ^ swz8;
    return *(const bf16x8*)&Bs[buf*16384 + row*64 + col];
  };

  f32x4 acc[8][4];
  #pragma unroll
  for (int i=0;i<8;++i)
    #pragma unroll
    for (int j=0;j<4;++j)
      acc[i][j] = (f32x4){0.f,0.f,0.f,0.f};

  // prologue: stage tile0 + tile1 fully; wait tile0 (tile1's 8 may fly)
  stageA(0,0); stageA(0,1); stageB(0,0); stageB(0,1);
  stageA(1,0); stageA(1,1); stageB(1,0); stageB(1,1);
  asm volatile("s_waitcnt vmcnt(8)" ::: "memory");
  __builtin_amdgcn_s_barrier();

  bf16x8 av[8][2], bv[4][2];

  #pragma unroll 2
  for (int kt = 0; kt < NKT; ++kt){
    const int buf = kt & 1;

    // read ALL 24 fragments of this K-tile into registers
    #pragma unroll
    for (int i=0;i<8;++i){ av[i][0]=lda(buf,i,0); av[i][1]=lda(buf,i,1); }
    #pragma unroll
    for (int j=0;j<4;++j){ bv[j][0]=ldb(buf,j,0); bv[j][1]=ldb(buf,j,1); }
    asm volatile("s_waitcnt lgkmcnt(0)" ::: "memory");
    __builtin_amdgcn_sched_barrier(0);
    __builtin_amdgcn_s_barrier();          // all waves' reads of buf retired

    // buf is now free: prefetch tile kt+2 into it (2-deep, counted)
    stageA(kt+2, 0); stageA(kt+2, 1);
    stageB(kt+2, 0); stageB(kt+2, 1);
    __builtin_amdgcn_sched_barrier(0);

    __builtin_amdgcn_s_setprio(1);
    #pragma unroll
    for (int ks=0;ks<2;++ks)
      #pragma unroll
      for (int i=0;i<8;++i)
        #pragma unroll
        for (int j=0;j<4;++j)
          acc[i][j] = __builtin_amdgcn_mfma_f32_16x16x32_bf16(av[i][ks], bv[j][ks], acc[i][j], 0,0,0);
    __builtin_amdgcn_s_setprio(0);

    if (kt < NKT-2)       asm volatile("s_waitcnt vmcnt(8)" ::: "memory");
    else if (kt == NKT-2) asm volatile("s_waitcnt vmcnt(0)" ::: "memory");
    __builtin_amdgcn_s_barrier();
  }

  #pragma unroll
  for (int mi=0;mi<8;++mi){
    #pragma unroll
    for (int r=0;r<4;++r){
      const long mg = m0 + wr*128 + mi*16 + lhi*4 + r;
      const bool mz = (mode==1 || mode==2) ? (mask[mg] != 0) : false;
      #pragma unroll
      for (int ni=0;ni<4;++ni){
        const int ng = n0 + wc*64 + ni*16 + l15;
        float v = acc[mi][ni][r];
        if (mode==1) v = (v > 0.f) ? (v + 1.f) : __expf(v);
        if (mz) v = 0.f;
        if (mode==3) OF[mg*NE + ng] = v;
        else         Obf[mg*NE + ng] = f2bf(v);
      }
    }
  }
}

// ============ Q-projection GEMM with fused linear-attention epilogue ============
__global__ __launch_bounds__(512, 2) void gemm_q_attn(
    const unsigned short* __restrict__ A,
    const unsigned short* __restrict__ Wq,
    const unsigned short* __restrict__ KVfrag,
    unsigned short* __restrict__ attnb)
{
  __shared__ __align__(16) unsigned short As[2*256*64];
  __shared__ __align__(16) unsigned short Bs[2*256*64];

  const int nwg = (int)gridDim.x;
  const int bx  = (int)blockIdx.x;
  const int swz = (bx & 7) * (nwg >> 3) + (bx >> 3);
  const long m0 = (long)(swz >> 2) * 256;
  const int  n0 = (swz & 3) * 256;

  const int tid = (int)threadIdx.x;
  const int l   = tid & 63;
  const int wv  = tid >> 6;
  const int wr  = wv >> 2;
  const int wc  = wv & 3;
  const int l15 = l & 15;
  const int lhi = l >> 4;
  const int swz8 = (l & 7) * 8;

  const int srow = wv*16 + (l >> 3);
  const int scol = ((l & 7) * 8) ^ ((l >> 3) << 3);

  auto stageA = [&](int st, int h){
    if (st >= NKT) return;
    const long col = (long)st*64 + scol;
    #pragma unroll
    for (int is = 0; is < 2; ++is)
      gload16(A + (m0 + h*128 + srow + is*8)*NE + col,
              &As[(st & 1)*16384 + h*8192 + (wv*2 + is)*512]);
  };
  auto stageB = [&](int st, int h){
    if (st >= NKT) return;
    const long col = (long)st*64 + scol;
    #pragma unroll
    for (int is = 0; is < 2; ++is)
      gload16(Wq + (long)(n0 + h*128 + srow + is*8)*NE + col,
              &Bs[(st & 1)*16384 + h*8192 + (wv*2 + is)*512]);
  };

  auto lda = [&](int buf, int mi, int ks)->bf16x8 {
    const int row = wr*128 + mi*16 + l15;
    const int col = (ks*32 + lhi*8) ^ swz8;
    return *(const bf16x8*)&As[buf*16384 + row*64 + col];
  };
  auto ldb = [&](int buf, int ni, int ks)->bf16x8 {
    const int row = wc*64 + ni*16 + l15;
    const int col = (ks*32 + lhi*8) ^ swz8;
    return *(const bf16x8*)&Bs[buf*16384 + row*64 + col];
  };

  f32x4 acc[8][4];
  #pragma unroll
  for (int i=0;i<8;++i)
    #pragma unroll
    for (int j=0;j<4;++j)
      acc[i][j] = (f32x4){0.f,0.f,0.f,0.f};

  stageA(0,0); stageA(0,1); stageB(0,0); stageB(0,1);
  stageA(1,0); stageA(1,1); stageB(1,0); stageB(1,1);
  asm volatile("s_waitcnt vmcnt(8)" ::: "memory");
  __builtin_amdgcn_s_barrier();

  bf16x8 av[8][2], bv[4][2];

  #pragma unroll 2
  for (int kt = 0; kt < NKT; ++kt){
    const int buf = kt & 1;

    #pragma unroll
    for (int i=0;i<8;++i){ av[i][0]=lda(buf,i,0); av[i][1]=lda(buf,i,1); }
    #pragma unroll
    for (int j=0;j<4;++j){ bv[j][0]=ldb(buf,j,0); bv[j][1]=ldb(buf,j,1); }
    asm volatile("s_waitcnt lgkmcnt(0)" ::: "memory");
    __builtin_amdgcn_sched_barrier(0);
    __builtin_amdgcn_s_barrier();

    stageA(kt+2, 0); stageA(kt+2, 1);
    stageB(kt+2, 0); stageB(kt+2, 1);
    __builtin_amdgcn_sched_barrier(0);

    __builtin_amdgcn_s_setprio(1);
    #pragma unroll
    for (int ks=0;ks<2;++ks)
      #pragma unroll
      for (int i=0;i<8;++i)
        #pragma unroll
        for (int j=0;j<4;++j)
          acc[i][j] = __builtin_amdgcn_mfma_f32_16x16x32_bf16(av[i][ks], bv[j][ks], acc[i][j], 0,0,0);
    __builtin_amdgcn_s_setprio(0);

    if (kt < NKT-2)       asm volatile("s_waitcnt vmcnt(8)" ::: "memory");
    else if (kt == NKT-2) asm volatile("s_waitcnt vmcnt(0)" ::: "memory");
    __builtin_amdgcn_s_barrier();
  }

  // ---- fused attn epilogue (per-wave private; no cross-wave sync) ----
  const int b  = (int)(m0 >> 13);             // 8192 rows per batch
  const int h  = (swz & 3)*4 + wc;            // this wave's head
  const long bh = (long)(b*16 + h);
  unsigned short* pool = (wv < 4) ? &As[wv*8192] : &Bs[(wv-4)*8192];  // 128 rows x 64 shorts

  // q = elu(acc)+1 -> bf16 -> pool (row stride 128B, XOR-swizzled)
  #pragma unroll
  for (int mi=0;mi<8;++mi){
    #pragma unroll
    for (int r=0;r<4;++r){
      const int row = mi*16 + lhi*4 + r;
      #pragma unroll
      for (int ni=0;ni<4;++ni){
        float v = acc[mi][ni][r];
        v = (v > 0.f) ? (v + 1.f) : __expf(v);
        const int colb = (ni*16 + l15)*2;
        *(unsigned short*)((char*)pool + row*128 + (colb ^ ((row & 7) << 4))) = f2bf(v);
      }
    }
  }

  // this head's KV fragments: [ks 0..3][nt 0..4][lane][8]
  bf16x8 bfv[4][5];
  #pragma unroll
  for (int ks=0; ks<4; ++ks)
    #pragma unroll
    for (int nt=0; nt<5; ++nt)
      bfv[ks][nt] = *(const bf16x8*)(KVfrag + bh*10240 + (ks*5+nt)*512 + l*8);

  asm volatile("s_waitcnt lgkmcnt(0)" ::: "memory");
  __builtin_amdgcn_sched_barrier(0);

  const int swzb = (l15 & 7) << 4;
  #pragma unroll
  for (int rt=0; rt<8; ++rt){
    const int rb = (rt*16 + l15)*128;
    bf16x8 qa0 = *(const bf16x8*)((const char*)pool + rb + ((lhi*16) ^ swzb));
    bf16x8 qa1 = *(const bf16x8*)((const char*)pool + rb + ((64 + lhi*16) ^ swzb));
    f32x4 at[5];
    #pragma unroll
    for (int nt=0; nt<5; ++nt){
      at[nt] = (f32x4){0.f,0.f,0.f,0.f};
      at[nt] = __builtin_amdgcn_mfma_f32_16x16x32_bf16(qa0, bfv[0][nt], at[nt], 0,0,0);
      at[nt] = __builtin_amdgcn_mfma_f32_16x16x32_bf16(qa1, bfv[1][nt], at[nt], 0,0,0);
      at[nt] = __builtin_amdgcn_mfma_f32_16x16x32_bf16(qa0, bfv[2][nt], at[nt], 0,0,0);
      at[nt] = __builtin_amdgcn_mfma_f32_16x16x32_bf16(qa1, bfv[3][nt], at[nt], 0,0,0);
    }
    float dv[4];
    #pragma unroll
    for (int e=0;e<4;++e){
      float d = __shfl(at[4][e], l & 48, 64);
      dv[e] = 1.f / (d + 1e-6f);
    }
    #pragma unroll
    for (int nt=0; nt<4; ++nt){
      #pragma unroll
      for (int e=0;e<4;++e){
        const int row = rt*16 + lhi*4 + e;
        const int colb = (nt*16 + l15)*2;
        *(unsigned short*)((char*)pool + row*128 + (colb ^ ((row & 7) << 4))) = f2bf(at[nt][e] * dv[e]);
      }
    }
  }

  asm volatile("s_waitcnt lgkmcnt(0)" ::: "memory");
  __builtin_amdgcn_sched_barrier(0);
  // coalesced store: 8 lanes cover one 128B row
  #pragma unroll
  for (int c=0;c<16;++c){
    const int r = c*8 + (l >> 3);
    bf16x8 vv = *(const bf16x8*)((const char*)pool + r*128 + ((((l&7) ^ (r & 7))) << 4));
    *(bf16x8*)(attnb + (m0 + wr*128 + r)*NE + h*ND + (l&7)*8) = vv;
  }
}

// ---- kv_reduce: partial[bh][chunk] = sum over 256 rows of K^T V (64x64) + Ksum ----
__global__ __launch_bounds__(256) void kv_reduce(const unsigned short* __restrict__ K,
                                                 const unsigned short* __restrict__ V,
                                                 float* __restrict__ part){
  __shared__ float lds[2*64*68 + 192];
  float* Ksf = lds;
  float* Vsf = lds + 64*68;
  float* kcorner = lds + 2*64*68;

  const int bid = blockIdx.x;
  const int bh = bid >> 5;
  const int chunk = bid & 31;
  const int b = bh >> 4, h = bh & 15;
  const int t = threadIdx.x, w = t >> 6, l = t & 63;
  const int dg = l & 7, eg = l >> 3;
  const int d0 = dg*8, e0 = eg*8;
  const long base = ((long)b*NS + (long)chunk*256)*NE + h*ND;

  f32x4 acc[8][2];
  #pragma unroll
  for (int j=0;j<8;++j){ acc[j][0]=(f32x4){0,0,0,0}; acc[j][1]=(f32x4){0,0,0,0}; }
  f32x4 ksa = (f32x4){0,0,0,0}, ksb = (f32x4){0,0,0,0};

  for (int sc = 0; sc < 4; ++sc){
    if (sc) __syncthreads();
    const long rbase = base + (long)sc*64*NE;
    #pragma unroll
    for (int p = 0; p < 2; ++p){
      const int g = p*256 + t;
      const int row = g >> 3, cg = (g & 7)*8;
      u16x8 ku = *(const u16x8*)(K + rbase + (long)row*NE + cg);
      u16x8 vu = *(const u16x8*)(V + rbase + (long)row*NE + cg);
      #pragma unroll
      for (int j=0;j<8;++j){
        Ksf[row*68 + cg + j] = bf2f(ku[j]);
        Vsf[row*68 + cg + j] = bf2f(vu[j]);
      }
    }
    __syncthreads();
    #pragma unroll 2
    for (int i = 0; i < 16; ++i){
      const int r = w*16 + i;
      f32x4 k0 = *(const f32x4*)&Ksf[r*68 + d0];
      f32x4 k1 = *(const f32x4*)&Ksf[r*68 + d0 + 4];
      f32x4 v0 = *(const f32x4*)&Vsf[r*68 + e0];
      f32x4 v1 = *(const f32x4*)&Vsf[r*68 + e0 + 4];
      #pragma unroll
      for (int j=0;j<4;++j){
        acc[j][0]   += k0[j]*v0;  acc[j][1]   += k0[j]*v1;
        acc[4+j][0] += k1[j]*v0;  acc[4+j][1] += k1[j]*v1;
      }
      if (eg == 0){ ksa += k0; ksb += k1; }
    }
  }

  __syncthreads();
  if (w >= 1 && eg == 0){
    *(f32x4*)&kcorner[(w-1)*64 + d0]     = ksa;
    *(f32x4*)&kcorner[(w-1)*64 + d0 + 4] = ksb;
  }
  if (w >= 2){
    float* reg = (w==2) ? Ksf : Vsf;
    #pragma unroll
    for (int j=0;j<8;++j)
      #pragma unroll
      for (int q=0;q<2;++q)
        *(f32x4*)&reg[l*68 + (j*2+q)*4] = acc[j][q];
  }
  __syncthreads();
  if (w < 2){
    float* reg = (w==0) ? Ksf : Vsf;
    #pragma unroll
    for (int j=0;j<8;++j)
      #pragma unroll
      for (int q=0;q<2;++q)
        acc[j][q] += *(const f32x4*)&reg[l*68 + (j*2+q)*4];
  }
  __syncthreads();
  if (w == 1){
    #pragma unroll
    for (int j=0;j<8;++j)
      #pragma unroll
      for (int q=0;q<2;++q)
        *(f32x4*)&Ksf[l*68 + (j*2+q)*4] = acc[j][q];
  }
  __syncthreads();
  if (w == 0){
    #pragma unroll
    for (int j=0;j<8;++j)
      #pragma unroll
      for (int q=0;q<2;++q)
        acc[j][q] += *(const f32x4*)&Ksf[l*68 + (j*2+q)*4];
    float* po = part + (long)(bh*32 + chunk)*4160;
    #pragma unroll
    for (int j=0;j<8;++j)
      #pragma unroll
      for (int q=0;q<2;++q)
        *(f32x4*)&po[(d0 + j)*64 + e0 + q*4] = acc[j][q];
    if (eg == 0){
      #pragma unroll
      for (int i=0;i<3;++i){
        ksa += *(const f32x4*)&kcorner[i*64 + d0];
        ksb += *(const f32x4*)&kcorner[i*64 + d0 + 4];
      }
      *(f32x4*)&po[4096 + d0]     = ksa;
      *(f32x4*)&po[4096 + d0 + 4] = ksb;
    }
  }
}

// ---- kv_finish: sum partials, emit KV' = [KV | Ksum] as hi/lo bf16 B-fragments ----
__global__ __launch_bounds__(256) void kv_finish(const float* __restrict__ part,
                                                 unsigned short* __restrict__ KVfrag){
  __shared__ float KVf[64*65 + 32];
  const int bh = blockIdx.x, t = threadIdx.x;
  const float* pb = part + (long)bh*32*4160;

  #pragma unroll
  for (int p = 0; p < 4; ++p){
    int g = p*256 + t;
    f32x4 s = (f32x4){0.f,0.f,0.f,0.f};
    for (int c = 0; c < 32; ++c) s += *(const f32x4*)&pb[c*4160 + g*4];
    int d = g >> 4, e = (g & 15)*4;
    KVf[d*65 + e+0] = s[0];
    KVf[d*65 + e+1] = s[1];
    KVf[d*65 + e+2] = s[2];
    KVf[d*65 + e+3] = s[3];
  }
  if (t < 16){
    f32x4 s = (f32x4){0.f,0.f,0.f,0.f};
    for (int c = 0; c < 32; ++c) s += *(const f32x4*)&pb[c*4160 + 4096 + t*4];
    #pragma unroll
    for (int j=0;j<4;++j) KVf[(t*4+j)*65 + 64] = s[j];
  }
  __syncthreads();

  for (int idx = t; idx < 10240; idx += 256){
    int j   = idx & 7;
    int lfr = (idx >> 3) & 63;
    int grp = idx >> 9;
    int nt  = grp % 5, ks = grp / 5;
    int kk  = (ks & 1)*32 + (lfr >> 4)*8 + j;
    int n   = nt*16 + (lfr & 15);
    float v = (n <= 64) ? KVf[kk*65 + n] : 0.f;
    unsigned short hi = f2bf(v);
    unsigned short o  = (ks >> 1) ? f2bf(v - bf2f(hi)) : hi;
    KVfrag[(long)bh*10240 + idx] = o;
  }
}

extern "C" void kernel_launch(void* const* d_in, const int* in_sizes, int n_in,
                              void* d_out, int out_size, void* d_ws, size_t ws_size,
                              hipStream_t stream){
  (void)in_sizes; (void)n_in; (void)out_size; (void)ws_size;
  const float* x    = (const float*)d_in[0];
  const void*  mraw = d_in[1];
  const float* Wq   = (const float*)d_in[2];
  const float* Wk   = (const float*)d_in[3];
  const float* Wv   = (const float*)d_in[4];
  const float* Wo   = (const float*)d_in[5];
  float* out = (float*)d_out;
  char* ws = (char*)d_ws;

  unsigned short* xb  = (unsigned short*)(ws + 0L);           // 64 MB bf16 x (lives until q_attn)
  unsigned short* Wqb = (unsigned short*)(ws + 67108864L);
  unsigned short* Wkb = (unsigned short*)(ws + 69206016L);
  unsigned short* Wvb = (unsigned short*)(ws + 71303168L);
  unsigned short* Wob = (unsigned short*)(ws + 73400320L);
  unsigned short* Qb  = (unsigned short*)(ws + 75497472L);    // 64 MB: kv partials, then attn
  unsigned short* Kb  = (unsigned short*)(ws + 142606336L);
  unsigned short* Vb  = (unsigned short*)(ws + 209715200L);
  unsigned short* KVfrag = (unsigned short*)(ws + 276824064L);
  unsigned char* mask_u8 = (unsigned char*)(ws + 278462464L);
  float* part = (float*)Qb;               // 34 MB partials (consumed by kv_finish
  unsigned short* attnb = Qb;             // before q_attn overwrites with attn)

  mask_prep<<<32, 256, 0, stream>>>(mraw, mask_u8);

  CastJobs J;
  J.src[0]=x;  J.dst[0]=xb;  J.n4[0]=NM*NE/4;
  J.src[1]=Wq; J.dst[1]=Wqb; J.n4[1]=NE*NE/4;
  J.src[2]=Wk; J.dst[2]=Wkb; J.n4[2]=NE*NE/4;
  J.src[3]=Wv; J.dst[3]=Wvb; J.n4[3]=NE*NE/4;
  J.src[4]=Wo; J.dst[4]=Wob; J.n4[4]=NE*NE/4;
  castk<<<dim3(2048,5), 256, 0, stream>>>(J);

  // K,V projections
  gemm256<<<dim3(512,2), 512, 0, stream>>>(xb, Wkb, Wvb, Kb, Vb, nullptr, mask_u8, -1);

  kv_reduce<<<dim3(2048), 256, 0, stream>>>(Kb, Vb, part);
  kv_finish<<<dim3(64), 256, 0, stream>>>(part, KVfrag);

  // Q projection + fused attn (writes attn into Qb region)
  gemm_q_attn<<<dim3(512), 512, 0, stream>>>(xb, Wqb, KVfrag, attnb);

  // final projection: out = attn @ Wo^T (f32 out)
  gemm256<<<dim3(512,1), 512, 0, stream>>>(attnb, Wob, Wob, nullptr, nullptr, out, mask_u8, 3);
}

// Round 11
// 455.692 us; speedup vs baseline: 1.5158x; 1.5158x over previous
//
#include <hip/hip_runtime.h>

#define NB 4
#define NS 8192
#define NE 1024
#define NH 16
#define ND 64
#define NM (NB*NS)          // 32768 rows
#define NKT 16              // K-tiles of 64 in NE=1024

typedef __bf16 bf16x8 __attribute__((ext_vector_type(8)));
typedef float  f32x4  __attribute__((ext_vector_type(4)));
typedef unsigned short u16x8 __attribute__((ext_vector_type(8)));

__device__ __forceinline__ unsigned short f2bf(float f){
  unsigned int u = __float_as_uint(f);
  u += 0x7FFFu + ((u >> 16) & 1u);
  return (unsigned short)(u >> 16);
}
__device__ __forceinline__ float bf2f(unsigned short h){
  return __uint_as_float(((unsigned int)h) << 16);
}
__device__ __forceinline__ void gload16(const void* g, void* lds){
  __builtin_amdgcn_global_load_lds(
      (__attribute__((address_space(1))) unsigned int*)g,
      (__attribute__((address_space(3))) unsigned int*)lds, 16, 0, 0);
}

// ---- mask canonicalization: detect int32 vs byte layout on-device ----
__global__ void mask_prep(const void* mraw, unsigned char* mask_u8){
  __shared__ int flag_s;
  if (threadIdx.x == 0) flag_s = 0;
  __syncthreads();
  const unsigned int* mi = (const unsigned int*)mraw;
  int bad = 0;
  for (int i = threadIdx.x; i < 4096; i += 256) bad |= (mi[i] > 1u) ? 1 : 0;
  if (bad) atomicOr(&flag_s, 1);
  __syncthreads();
  const int isbyte = flag_s;
  const unsigned char* mb = (const unsigned char*)mraw;
  int stride = gridDim.x * blockDim.x;
  for (int i = blockIdx.x*blockDim.x + threadIdx.x; i < NM; i += stride)
    mask_u8[i] = isbyte ? (unsigned char)(mb[i] != 0) : (unsigned char)(mi[i] != 0);
}

// ---- f32 -> bf16 cast ----
struct CastJobs {
  const float* src[5];
  unsigned short* dst[5];
  int n4[5];
};

__global__ __launch_bounds__(256) void castk(CastJobs J){
  int j = blockIdx.y;
  const float* s = J.src[j];
  unsigned short* d = J.dst[j];
  int n4 = J.n4[j];
  int stride = gridDim.x * blockDim.x;
  for (int i = blockIdx.x*blockDim.x + threadIdx.x; i < n4; i += stride){
    float4 v = *(const float4*)(s + (long)i*4);
    ushort4 o;
    o.x = f2bf(v.x); o.y = f2bf(v.y); o.z = f2bf(v.z); o.w = f2bf(v.w);
    *(ushort4*)(d + (long)i*4) = o;
  }
}

// ============ 256x256 bf16 GEMM: 4 single-barrier phases/K-tile ============
// mode 1: bf16, elu+1+mask (K) | 2: bf16, mask (V) | 3: f32 out, plain (@Wo^T)
// Compiler-scheduled lgkmcnt (no manual full drains): every ds_read is
// consumed by an MFMA issued before the phase-end barrier, so all reads
// retire before any wave crosses it; stages for tile kt+2 only target
// regions whose reads ended in earlier phases.
__global__ __launch_bounds__(512, 2) void gemm256(
    const unsigned short* __restrict__ A,
    const unsigned short* __restrict__ W1,
    const unsigned short* __restrict__ W2,
    unsigned short* __restrict__ O1,
    unsigned short* __restrict__ O2,
    float* __restrict__ OF,
    const unsigned char* __restrict__ mask,
    int modeSel)
{
  __shared__ __align__(16) unsigned short As[2*256*64];
  __shared__ __align__(16) unsigned short Bs[2*256*64];

  const int mode = (modeSel < 0) ? (int)blockIdx.y + 1 : modeSel;
  const unsigned short* Bw = (mode==1) ? W1 : (mode==2) ? W2 : W1;
  unsigned short* Obf = (mode==1) ? O1 : O2;

  const int nwg = (int)gridDim.x;
  const int bx  = (int)blockIdx.x;
  const int swz = (bx & 7) * (nwg >> 3) + (bx >> 3);
  const long m0 = (long)(swz >> 2) * 256;
  const int  n0 = (swz & 3) * 256;

  const int tid = (int)threadIdx.x;
  const int l   = tid & 63;
  const int wv  = tid >> 6;
  const int wr  = wv >> 2;
  const int wc  = wv & 3;
  const int l15 = l & 15;
  const int lhi = l >> 4;
  const int swz8 = (l & 7) * 8;

  const int srow = wv*16 + (l >> 3);
  const int scol = ((l & 7) * 8) ^ ((l >> 3) << 3);

  auto stageA = [&](int st, int h){
    if (st >= NKT) return;
    const long col = (long)st*64 + scol;
    #pragma unroll
    for (int is = 0; is < 2; ++is)
      gload16(A + (m0 + h*128 + srow + is*8)*NE + col,
              &As[(st & 1)*16384 + h*8192 + (wv*2 + is)*512]);
  };
  auto stageB = [&](int st, int h){
    if (st >= NKT) return;
    const long col = (long)st*64 + scol;
    #pragma unroll
    for (int is = 0; is < 2; ++is)
      gload16(Bw + (long)(n0 + h*128 + srow + is*8)*NE + col,
              &Bs[(st & 1)*16384 + h*8192 + (wv*2 + is)*512]);
  };

  auto lda = [&](int buf, int mi, int ks)->bf16x8 {
    const int row = wr*128 + mi*16 + l15;
    const int col = (ks*32 + lhi*8) ^ swz8;
    return *(const bf16x8*)&As[buf*16384 + row*64 + col];
  };
  auto ldb = [&](int buf, int ni, int ks)->bf16x8 {
    const int row = wc*64 + ni*16 + l15;
    const int col = (ks*32 + lhi*8) ^ swz8;
    return *(const bf16x8*)&Bs[buf*16384 + row*64 + col];
  };

  f32x4 acc[8][4];
  #pragma unroll
  for (int i=0;i<8;++i)
    #pragma unroll
    for (int j=0;j<4;++j)
      acc[i][j] = (f32x4){0.f,0.f,0.f,0.f};

  stageA(0,0); stageA(0,1); stageB(0,0); stageB(0,1);
  stageA(1,0); stageA(1,1); stageB(1,0); stageB(1,1);
  asm volatile("s_waitcnt vmcnt(8)" ::: "memory");
  __builtin_amdgcn_s_barrier();

  bf16x8 a0[4][2], a1[4][2], b0[2][2], b1[2][2];

  #pragma unroll 2
  for (int kt = 0; kt < NKT; ++kt){
    const int buf = kt & 1;

    // ---- phase 0: read A(qm0)+B(qn0); MFMA quad (qm0,qn0)
    #pragma unroll
    for (int i=0;i<4;++i){ a0[i][0]=lda(buf,i,0); a0[i][1]=lda(buf,i,1); }
    #pragma unroll
    for (int j=0;j<2;++j){ b0[j][0]=ldb(buf,j,0); b0[j][1]=ldb(buf,j,1); }
    __builtin_amdgcn_s_setprio(1);
    #pragma unroll
    for (int ks=0;ks<2;++ks)
      #pragma unroll
      for (int i=0;i<4;++i)
        #pragma unroll
        for (int j=0;j<2;++j)
          acc[i][j] = __builtin_amdgcn_mfma_f32_16x16x32_bf16(a0[i][ks], b0[j][ks], acc[i][j], 0,0,0);
    __builtin_amdgcn_s_setprio(0);
    __builtin_amdgcn_s_barrier();

    // ---- phase 1: read A(qm1); MFMA quad (qm1,qn0)   [last A-read of buf]
    #pragma unroll
    for (int i=0;i<4;++i){ a1[i][0]=lda(buf,4+i,0); a1[i][1]=lda(buf,4+i,1); }
    __builtin_amdgcn_s_setprio(1);
    #pragma unroll
    for (int ks=0;ks<2;++ks)
      #pragma unroll
      for (int i=0;i<4;++i)
        #pragma unroll
        for (int j=0;j<2;++j)
          acc[4+i][j] = __builtin_amdgcn_mfma_f32_16x16x32_bf16(a1[i][ks], b0[j][ks], acc[4+i][j], 0,0,0);
    __builtin_amdgcn_s_setprio(0);
    __builtin_amdgcn_s_barrier();

    // ---- phase 2: read B(qn1) [last B-read]; stage A(kt+2); MFMA (qm1,qn1)
    #pragma unroll
    for (int j=0;j<2;++j){ b1[j][0]=ldb(buf,2+j,0); b1[j][1]=ldb(buf,2+j,1); }
    stageA(kt+2, 0); stageA(kt+2, 1);
    __builtin_amdgcn_sched_barrier(0);
    __builtin_amdgcn_s_setprio(1);
    #pragma unroll
    for (int ks=0;ks<2;++ks)
      #pragma unroll
      for (int i=0;i<4;++i)
        #pragma unroll
        for (int j=0;j<2;++j)
          acc[4+i][2+j] = __builtin_amdgcn_mfma_f32_16x16x32_bf16(a1[i][ks], b1[j][ks], acc[4+i][2+j], 0,0,0);
    __builtin_amdgcn_s_setprio(0);
    __builtin_amdgcn_s_barrier();

    // ---- phase 3: stage B(kt+2); MFMA quad (qm0,qn1); counted vmcnt
    stageB(kt+2, 0); stageB(kt+2, 1);
    __builtin_amdgcn_sched_barrier(0);
    __builtin_amdgcn_s_setprio(1);
    #pragma unroll
    for (int ks=0;ks<2;++ks)
      #pragma unroll
      for (int i=0;i<4;++i)
        #pragma unroll
        for (int j=0;j<2;++j)
          acc[i][2+j] = __builtin_amdgcn_mfma_f32_16x16x32_bf16(a0[i][ks], b1[j][ks], acc[i][2+j], 0,0,0);
    __builtin_amdgcn_s_setprio(0);
    if (kt < NKT-2)       asm volatile("s_waitcnt vmcnt(8)" ::: "memory");
    else if (kt == NKT-2) asm volatile("s_waitcnt vmcnt(0)" ::: "memory");
    __builtin_amdgcn_s_barrier();
  }

  #pragma unroll
  for (int mi=0;mi<8;++mi){
    #pragma unroll
    for (int r=0;r<4;++r){
      const long mg = m0 + wr*128 + mi*16 + lhi*4 + r;
      const bool mz = (mode==1 || mode==2) ? (mask[mg] != 0) : false;
      #pragma unroll
      for (int ni=0;ni<4;++ni){
        const int ng = n0 + wc*64 + ni*16 + l15;
        float v = acc[mi][ni][r];
        if (mode==1) v = (v > 0.f) ? (v + 1.f) : __expf(v);
        if (mz) v = 0.f;
        if (mode==3) OF[mg*NE + ng] = v;
        else         Obf[mg*NE + ng] = f2bf(v);
      }
    }
  }
}

// ============ Q-projection GEMM with fused linear-attention epilogue ============
__global__ __launch_bounds__(512, 2) void gemm_q_attn(
    const unsigned short* __restrict__ A,
    const unsigned short* __restrict__ Wq,
    const unsigned short* __restrict__ KVfrag,
    unsigned short* __restrict__ attnb)
{
  __shared__ __align__(16) unsigned short As[2*256*64];
  __shared__ __align__(16) unsigned short Bs[2*256*64];

  const int nwg = (int)gridDim.x;
  const int bx  = (int)blockIdx.x;
  const int swz = (bx & 7) * (nwg >> 3) + (bx >> 3);
  const long m0 = (long)(swz >> 2) * 256;
  const int  n0 = (swz & 3) * 256;

  const int tid = (int)threadIdx.x;
  const int l   = tid & 63;
  const int wv  = tid >> 6;
  const int wr  = wv >> 2;
  const int wc  = wv & 3;
  const int l15 = l & 15;
  const int lhi = l >> 4;
  const int swz8 = (l & 7) * 8;

  const int srow = wv*16 + (l >> 3);
  const int scol = ((l & 7) * 8) ^ ((l >> 3) << 3);

  auto stageA = [&](int st, int h){
    if (st >= NKT) return;
    const long col = (long)st*64 + scol;
    #pragma unroll
    for (int is = 0; is < 2; ++is)
      gload16(A + (m0 + h*128 + srow + is*8)*NE + col,
              &As[(st & 1)*16384 + h*8192 + (wv*2 + is)*512]);
  };
  auto stageB = [&](int st, int h){
    if (st >= NKT) return;
    const long col = (long)st*64 + scol;
    #pragma unroll
    for (int is = 0; is < 2; ++is)
      gload16(Wq + (long)(n0 + h*128 + srow + is*8)*NE + col,
              &Bs[(st & 1)*16384 + h*8192 + (wv*2 + is)*512]);
  };

  auto lda = [&](int buf, int mi, int ks)->bf16x8 {
    const int row = wr*128 + mi*16 + l15;
    const int col = (ks*32 + lhi*8) ^ swz8;
    return *(const bf16x8*)&As[buf*16384 + row*64 + col];
  };
  auto ldb = [&](int buf, int ni, int ks)->bf16x8 {
    const int row = wc*64 + ni*16 + l15;
    const int col = (ks*32 + lhi*8) ^ swz8;
    return *(const bf16x8*)&Bs[buf*16384 + row*64 + col];
  };

  f32x4 acc[8][4];
  #pragma unroll
  for (int i=0;i<8;++i)
    #pragma unroll
    for (int j=0;j<4;++j)
      acc[i][j] = (f32x4){0.f,0.f,0.f,0.f};

  stageA(0,0); stageA(0,1); stageB(0,0); stageB(0,1);
  stageA(1,0); stageA(1,1); stageB(1,0); stageB(1,1);
  asm volatile("s_waitcnt vmcnt(8)" ::: "memory");
  __builtin_amdgcn_s_barrier();

  bf16x8 a0[4][2], a1[4][2], b0[2][2], b1[2][2];

  #pragma unroll 2
  for (int kt = 0; kt < NKT; ++kt){
    const int buf = kt & 1;

    #pragma unroll
    for (int i=0;i<4;++i){ a0[i][0]=lda(buf,i,0); a0[i][1]=lda(buf,i,1); }
    #pragma unroll
    for (int j=0;j<2;++j){ b0[j][0]=ldb(buf,j,0); b0[j][1]=ldb(buf,j,1); }
    __builtin_amdgcn_s_setprio(1);
    #pragma unroll
    for (int ks=0;ks<2;++ks)
      #pragma unroll
      for (int i=0;i<4;++i)
        #pragma unroll
        for (int j=0;j<2;++j)
          acc[i][j] = __builtin_amdgcn_mfma_f32_16x16x32_bf16(a0[i][ks], b0[j][ks], acc[i][j], 0,0,0);
    __builtin_amdgcn_s_setprio(0);
    __builtin_amdgcn_s_barrier();

    #pragma unroll
    for (int i=0;i<4;++i){ a1[i][0]=lda(buf,4+i,0); a1[i][1]=lda(buf,4+i,1); }
    __builtin_amdgcn_s_setprio(1);
    #pragma unroll
    for (int ks=0;ks<2;++ks)
      #pragma unroll
      for (int i=0;i<4;++i)
        #pragma unroll
        for (int j=0;j<2;++j)
          acc[4+i][j] = __builtin_amdgcn_mfma_f32_16x16x32_bf16(a1[i][ks], b0[j][ks], acc[4+i][j], 0,0,0);
    __builtin_amdgcn_s_setprio(0);
    __builtin_amdgcn_s_barrier();

    #pragma unroll
    for (int j=0;j<2;++j){ b1[j][0]=ldb(buf,2+j,0); b1[j][1]=ldb(buf,2+j,1); }
    stageA(kt+2, 0); stageA(kt+2, 1);
    __builtin_amdgcn_sched_barrier(0);
    __builtin_amdgcn_s_setprio(1);
    #pragma unroll
    for (int ks=0;ks<2;++ks)
      #pragma unroll
      for (int i=0;i<4;++i)
        #pragma unroll
        for (int j=0;j<2;++j)
          acc[4+i][2+j] = __builtin_amdgcn_mfma_f32_16x16x32_bf16(a1[i][ks], b1[j][ks], acc[4+i][2+j], 0,0,0);
    __builtin_amdgcn_s_setprio(0);
    __builtin_amdgcn_s_barrier();

    stageB(kt+2, 0); stageB(kt+2, 1);
    __builtin_amdgcn_sched_barrier(0);
    __builtin_amdgcn_s_setprio(1);
    #pragma unroll
    for (int ks=0;ks<2;++ks)
      #pragma unroll
      for (int i=0;i<4;++i)
        #pragma unroll
        for (int j=0;j<2;++j)
          acc[i][2+j] = __builtin_amdgcn_mfma_f32_16x16x32_bf16(a0[i][ks], b1[j][ks], acc[i][2+j], 0,0,0);
    __builtin_amdgcn_s_setprio(0);
    if (kt < NKT-2)       asm volatile("s_waitcnt vmcnt(8)" ::: "memory");
    else if (kt == NKT-2) asm volatile("s_waitcnt vmcnt(0)" ::: "memory");
    __builtin_amdgcn_s_barrier();
  }

  // ---- fused attn epilogue (per-wave private; no cross-wave sync) ----
  const int b  = (int)(m0 >> 13);             // 8192 rows per batch
  const int h  = (swz & 3)*4 + wc;            // this wave's head
  const long bh = (long)(b*16 + h);
  unsigned short* pool = (wv < 4) ? &As[wv*8192] : &Bs[(wv-4)*8192];  // 128 rows x 64 shorts

  // q = elu(acc)+1 -> bf16 -> pool (row stride 128B, XOR-swizzled)
  #pragma unroll
  for (int mi=0;mi<8;++mi){
    #pragma unroll
    for (int r=0;r<4;++r){
      const int row = mi*16 + lhi*4 + r;
      #pragma unroll
      for (int ni=0;ni<4;++ni){
        float v = acc[mi][ni][r];
        v = (v > 0.f) ? (v + 1.f) : __expf(v);
        const int colb = (ni*16 + l15)*2;
        *(unsigned short*)((char*)pool + row*128 + (colb ^ ((row & 7) << 4))) = f2bf(v);
      }
    }
  }

  // this head's KV fragments: [ks 0..3][nt 0..4][lane][8]
  bf16x8 bfv[4][5];
  #pragma unroll
  for (int ks=0; ks<4; ++ks)
    #pragma unroll
    for (int nt=0; nt<5; ++nt)
      bfv[ks][nt] = *(const bf16x8*)(KVfrag + bh*10240 + (ks*5+nt)*512 + l*8);

  asm volatile("s_waitcnt lgkmcnt(0)" ::: "memory");
  __builtin_amdgcn_sched_barrier(0);

  const int swzb = (l15 & 7) << 4;
  #pragma unroll
  for (int rt=0; rt<8; ++rt){
    const int rb = (rt*16 + l15)*128;
    bf16x8 qa0 = *(const bf16x8*)((const char*)pool + rb + ((lhi*16) ^ swzb));
    bf16x8 qa1 = *(const bf16x8*)((const char*)pool + rb + ((64 + lhi*16) ^ swzb));
    f32x4 at[5];
    #pragma unroll
    for (int nt=0; nt<5; ++nt){
      at[nt] = (f32x4){0.f,0.f,0.f,0.f};
      at[nt] = __builtin_amdgcn_mfma_f32_16x16x32_bf16(qa0, bfv[0][nt], at[nt], 0,0,0);
      at[nt] = __builtin_amdgcn_mfma_f32_16x16x32_bf16(qa1, bfv[1][nt], at[nt], 0,0,0);
      at[nt] = __builtin_amdgcn_mfma_f32_16x16x32_bf16(qa0, bfv[2][nt], at[nt], 0,0,0);
      at[nt] = __builtin_amdgcn_mfma_f32_16x16x32_bf16(qa1, bfv[3][nt], at[nt], 0,0,0);
    }
    float dv[4];
    #pragma unroll
    for (int e=0;e<4;++e){
      float d = __shfl(at[4][e], l & 48, 64);
      dv[e] = 1.f / (d + 1e-6f);
    }
    #pragma unroll
    for (int nt=0; nt<4; ++nt){
      #pragma unroll
      for (int e=0;e<4;++e){
        const int row = rt*16 + lhi*4 + e;
        const int colb = (nt*16 + l15)*2;
        *(unsigned short*)((char*)pool + row*128 + (colb ^ ((row & 7) << 4))) = f2bf(at[nt][e] * dv[e]);
      }
    }
  }

  asm volatile("s_waitcnt lgkmcnt(0)" ::: "memory");
  __builtin_amdgcn_sched_barrier(0);
  // coalesced store: 8 lanes cover one 128B row
  #pragma unroll
  for (int c=0;c<16;++c){
    const int r = c*8 + (l >> 3);
    bf16x8 vv = *(const bf16x8*)((const char*)pool + r*128 + ((((l&7) ^ (r & 7))) << 4));
    *(bf16x8*)(attnb + (m0 + wr*128 + r)*NE + h*ND + (l&7)*8) = vv;
  }
}

// ---- kv_reduce: partial[bh][chunk] = sum over 256 rows of K^T V (64x64) + Ksum ----
__global__ __launch_bounds__(256) void kv_reduce(const unsigned short* __restrict__ K,
                                                 const unsigned short* __restrict__ V,
                                                 float* __restrict__ part){
  __shared__ float lds[2*64*68 + 192];
  float* Ksf = lds;
  float* Vsf = lds + 64*68;
  float* kcorner = lds + 2*64*68;

  const int bid = blockIdx.x;
  const int bh = bid >> 5;
  const int chunk = bid & 31;
  const int b = bh >> 4, h = bh & 15;
  const int t = threadIdx.x, w = t >> 6, l = t & 63;
  const int dg = l & 7, eg = l >> 3;
  const int d0 = dg*8, e0 = eg*8;
  const long base = ((long)b*NS + (long)chunk*256)*NE + h*ND;

  f32x4 acc[8][2];
  #pragma unroll
  for (int j=0;j<8;++j){ acc[j][0]=(f32x4){0,0,0,0}; acc[j][1]=(f32x4){0,0,0,0}; }
  f32x4 ksa = (f32x4){0,0,0,0}, ksb = (f32x4){0,0,0,0};

  for (int sc = 0; sc < 4; ++sc){
    if (sc) __syncthreads();
    const long rbase = base + (long)sc*64*NE;
    #pragma unroll
    for (int p = 0; p < 2; ++p){
      const int g = p*256 + t;
      const int row = g >> 3, cg = (g & 7)*8;
      u16x8 ku = *(const u16x8*)(K + rbase + (long)row*NE + cg);
      u16x8 vu = *(const u16x8*)(V + rbase + (long)row*NE + cg);
      #pragma unroll
      for (int j=0;j<8;++j){
        Ksf[row*68 + cg + j] = bf2f(ku[j]);
        Vsf[row*68 + cg + j] = bf2f(vu[j]);
      }
    }
    __syncthreads();
    #pragma unroll 2
    for (int i = 0; i < 16; ++i){
      const int r = w*16 + i;
      f32x4 k0 = *(const f32x4*)&Ksf[r*68 + d0];
      f32x4 k1 = *(const f32x4*)&Ksf[r*68 + d0 + 4];
      f32x4 v0 = *(const f32x4*)&Vsf[r*68 + e0];
      f32x4 v1 = *(const f32x4*)&Vsf[r*68 + e0 + 4];
      #pragma unroll
      for (int j=0;j<4;++j){
        acc[j][0]   += k0[j]*v0;  acc[j][1]   += k0[j]*v1;
        acc[4+j][0] += k1[j]*v0;  acc[4+j][1] += k1[j]*v1;
      }
      if (eg == 0){ ksa += k0; ksb += k1; }
    }
  }

  __syncthreads();
  if (w >= 1 && eg == 0){
    *(f32x4*)&kcorner[(w-1)*64 + d0]     = ksa;
    *(f32x4*)&kcorner[(w-1)*64 + d0 + 4] = ksb;
  }
  if (w >= 2){
    float* reg = (w==2) ? Ksf : Vsf;
    #pragma unroll
    for (int j=0;j<8;++j)
      #pragma unroll
      for (int q=0;q<2;++q)
        *(f32x4*)&reg[l*68 + (j*2+q)*4] = acc[j][q];
  }
  __syncthreads();
  if (w < 2){
    float* reg = (w==0) ? Ksf : Vsf;
    #pragma unroll
    for (int j=0;j<8;++j)
      #pragma unroll
      for (int q=0;q<2;++q)
        acc[j][q] += *(const f32x4*)&reg[l*68 + (j*2+q)*4];
  }
  __syncthreads();
  if (w == 1){
    #pragma unroll
    for (int j=0;j<8;++j)
      #pragma unroll
      for (int q=0;q<2;++q)
        *(f32x4*)&Ksf[l*68 + (j*2+q)*4] = acc[j][q];
  }
  __syncthreads();
  if (w == 0){
    #pragma unroll
    for (int j=0;j<8;++j)
      #pragma unroll
      for (int q=0;q<2;++q)
        acc[j][q] += *(const f32x4*)&Ksf[l*68 + (j*2+q)*4];
    float* po = part + (long)(bh*32 + chunk)*4160;
    #pragma unroll
    for (int j=0;j<8;++j)
      #pragma unroll
      for (int q=0;q<2;++q)
        *(f32x4*)&po[(d0 + j)*64 + e0 + q*4] = acc[j][q];
    if (eg == 0){
      #pragma unroll
      for (int i=0;i<3;++i){
        ksa += *(const f32x4*)&kcorner[i*64 + d0];
        ksb += *(const f32x4*)&kcorner[i*64 + d0 + 4];
      }
      *(f32x4*)&po[4096 + d0]     = ksa;
      *(f32x4*)&po[4096 + d0 + 4] = ksb;
    }
  }
}

// ---- kv_finish: sum partials, emit KV' = [KV | Ksum] as hi/lo bf16 B-fragments ----
__global__ __launch_bounds__(256) void kv_finish(const float* __restrict__ part,
                                                 unsigned short* __restrict__ KVfrag){
  __shared__ float KVf[64*65 + 32];
  const int bh = blockIdx.x, t = threadIdx.x;
  const float* pb = part + (long)bh*32*4160;

  #pragma unroll
  for (int p = 0; p < 4; ++p){
    int g = p*256 + t;
    f32x4 s = (f32x4){0.f,0.f,0.f,0.f};
    for (int c = 0; c < 32; ++c) s += *(const f32x4*)&pb[c*4160 + g*4];
    int d = g >> 4, e = (g & 15)*4;
    KVf[d*65 + e+0] = s[0];
    KVf[d*65 + e+1] = s[1];
    KVf[d*65 + e+2] = s[2];
    KVf[d*65 + e+3] = s[3];
  }
  if (t < 16){
    f32x4 s = (f32x4){0.f,0.f,0.f,0.f};
    for (int c = 0; c < 32; ++c) s += *(const f32x4*)&pb[c*4160 + 4096 + t*4];
    #pragma unroll
    for (int j=0;j<4;++j) KVf[(t*4+j)*65 + 64] = s[j];
  }
  __syncthreads();

  for (int idx = t; idx < 10240; idx += 256){
    int j   = idx & 7;
    int lfr = (idx >> 3) & 63;
    int grp = idx >> 9;
    int nt  = grp % 5, ks = grp / 5;
    int kk  = (ks & 1)*32 + (lfr >> 4)*8 + j;
    int n   = nt*16 + (lfr & 15);
    float v = (n <= 64) ? KVf[kk*65 + n] : 0.f;
    unsigned short hi = f2bf(v);
    unsigned short o  = (ks >> 1) ? f2bf(v - bf2f(hi)) : hi;
    KVfrag[(long)bh*10240 + idx] = o;
  }
}

extern "C" void kernel_launch(void* const* d_in, const int* in_sizes, int n_in,
                              void* d_out, int out_size, void* d_ws, size_t ws_size,
                              hipStream_t stream){
  (void)in_sizes; (void)n_in; (void)out_size; (void)ws_size;
  const float* x    = (const float*)d_in[0];
  const void*  mraw = d_in[1];
  const float* Wq   = (const float*)d_in[2];
  const float* Wk   = (const float*)d_in[3];
  const float* Wv   = (const float*)d_in[4];
  const float* Wo   = (const float*)d_in[5];
  float* out = (float*)d_out;
  char* ws = (char*)d_ws;

  unsigned short* xb  = (unsigned short*)(ws + 0L);           // 64 MB bf16 x (lives until q_attn)
  unsigned short* Wqb = (unsigned short*)(ws + 67108864L);
  unsigned short* Wkb = (unsigned short*)(ws + 69206016L);
  unsigned short* Wvb = (unsigned short*)(ws + 71303168L);
  unsigned short* Wob = (unsigned short*)(ws + 73400320L);
  unsigned short* Qb  = (unsigned short*)(ws + 75497472L);    // 64 MB: kv partials, then attn
  unsigned short* Kb  = (unsigned short*)(ws + 142606336L);
  unsigned short* Vb  = (unsigned short*)(ws + 209715200L);
  unsigned short* KVfrag = (unsigned short*)(ws + 276824064L);
  unsigned char* mask_u8 = (unsigned char*)(ws + 278462464L);
  float* part = (float*)Qb;               // 34 MB partials (consumed by kv_finish
  unsigned short* attnb = Qb;             // before q_attn overwrites with attn)

  mask_prep<<<32, 256, 0, stream>>>(mraw, mask_u8);

  CastJobs J;
  J.src[0]=x;  J.dst[0]=xb;  J.n4[0]=NM*NE/4;
  J.src[1]=Wq; J.dst[1]=Wqb; J.n4[1]=NE*NE/4;
  J.src[2]=Wk; J.dst[2]=Wkb; J.n4[2]=NE*NE/4;
  J.src[3]=Wv; J.dst[3]=Wvb; J.n4[3]=NE*NE/4;
  J.src[4]=Wo; J.dst[4]=Wob; J.n4[4]=NE*NE/4;
  castk<<<dim3(2048,5), 256, 0, stream>>>(J);

  // K,V projections
  gemm256<<<dim3(512,2), 512, 0, stream>>>(xb, Wkb, Wvb, Kb, Vb, nullptr, mask_u8, -1);

  kv_reduce<<<dim3(2048), 256, 0, stream>>>(Kb, Vb, part);
  kv_finish<<<dim3(64), 256, 0, stream>>>(part, KVfrag);

  // Q projection + fused attn (writes attn into Qb region)
  gemm_q_attn<<<dim3(512), 512, 0, stream>>>(xb, Wqb, KVfrag, attnb);

  // final projection: out = attn @ Wo^T (f32 out)
  gemm256<<<dim3(512,1), 512, 0, stream>>>(attnb, Wob, Wob, nullptr, nullptr, out, mask_u8, 3);
}

// Round 12
// 436.200 us; speedup vs baseline: 1.5835x; 1.0447x over previous
//
#include <hip/hip_runtime.h>

#define NB 4
#define NS 8192
#define NE 1024
#define NH 16
#define ND 64
#define NM (NB*NS)          // 32768 rows
#define NKT 16              // K-tiles of 64 in NE=1024

typedef __bf16 bf16x8 __attribute__((ext_vector_type(8)));
typedef float  f32x4  __attribute__((ext_vector_type(4)));
typedef unsigned short u16x8 __attribute__((ext_vector_type(8)));

__device__ __forceinline__ unsigned short f2bf(float f){
  unsigned int u = __float_as_uint(f);
  u += 0x7FFFu + ((u >> 16) & 1u);
  return (unsigned short)(u >> 16);
}
__device__ __forceinline__ float bf2f(unsigned short h){
  return __uint_as_float(((unsigned int)h) << 16);
}
__device__ __forceinline__ void gload16(const void* g, void* lds){
  __builtin_amdgcn_global_load_lds(
      (__attribute__((address_space(1))) unsigned int*)g,
      (__attribute__((address_space(3))) unsigned int*)lds, 16, 0, 0);
}

// ---- f32 -> bf16 cast (+ mask canonicalization as job 5) ----
struct CastJobs {
  const float* src[5];
  unsigned short* dst[5];
  int n4[5];
};

__global__ __launch_bounds__(256) void castk(CastJobs J, const void* mraw,
                                             unsigned char* mask_u8){
  int j = blockIdx.y;
  if (j == 5){
    // mask: detect int32 vs byte layout on-device, canonicalize to u8
    __shared__ int flag_s;
    if (threadIdx.x == 0) flag_s = 0;
    __syncthreads();
    const unsigned int* mi = (const unsigned int*)mraw;
    int bad = 0;
    for (int i = threadIdx.x; i < 4096; i += 256) bad |= (mi[i] > 1u) ? 1 : 0;
    if (bad) atomicOr(&flag_s, 1);
    __syncthreads();
    const int isbyte = flag_s;
    const unsigned char* mb = (const unsigned char*)mraw;
    int stride = gridDim.x * blockDim.x;
    for (int i = blockIdx.x*blockDim.x + threadIdx.x; i < NM; i += stride)
      mask_u8[i] = isbyte ? (unsigned char)(mb[i] != 0) : (unsigned char)(mi[i] != 0);
    return;
  }
  const float* s = J.src[j];
  unsigned short* d = J.dst[j];
  int n4 = J.n4[j];
  int stride = gridDim.x * blockDim.x;
  for (int i = blockIdx.x*blockDim.x + threadIdx.x; i < n4; i += stride){
    float4 v = *(const float4*)(s + (long)i*4);
    ushort4 o;
    o.x = f2bf(v.x); o.y = f2bf(v.y); o.z = f2bf(v.z); o.w = f2bf(v.w);
    *(ushort4*)(d + (long)i*4) = o;
  }
}

// ============ 256x256 bf16 GEMM: 4 single-barrier phases/K-tile ============
// mode 1: bf16, elu+1+mask (K) | 2: bf16, mask (V) | 3: f32 out, plain (@Wo^T)
__global__ __launch_bounds__(512, 2) void gemm256(
    const unsigned short* __restrict__ A,
    const unsigned short* __restrict__ W1,
    const unsigned short* __restrict__ W2,
    unsigned short* __restrict__ O1,
    unsigned short* __restrict__ O2,
    float* __restrict__ OF,
    const unsigned char* __restrict__ mask,
    int modeSel)
{
  __shared__ __align__(16) unsigned short As[2*256*64];
  __shared__ __align__(16) unsigned short Bs[2*256*64];

  const int mode = (modeSel < 0) ? (int)blockIdx.y + 1 : modeSel;
  const unsigned short* Bw = (mode==1) ? W1 : (mode==2) ? W2 : W1;
  unsigned short* Obf = (mode==1) ? O1 : O2;

  const int nwg = (int)gridDim.x;
  const int bx  = (int)blockIdx.x;
  const int swz = (bx & 7) * (nwg >> 3) + (bx >> 3);
  const long m0 = (long)(swz >> 2) * 256;
  const int  n0 = (swz & 3) * 256;

  const int tid = (int)threadIdx.x;
  const int l   = tid & 63;
  const int wv  = tid >> 6;
  const int wr  = wv >> 2;
  const int wc  = wv & 3;
  const int l15 = l & 15;
  const int lhi = l >> 4;
  const int swz8 = (l & 7) * 8;

  const int srow = wv*16 + (l >> 3);
  const int scol = ((l & 7) * 8) ^ ((l >> 3) << 3);

  auto stageA = [&](int st, int h){
    if (st >= NKT) return;
    const long col = (long)st*64 + scol;
    #pragma unroll
    for (int is = 0; is < 2; ++is)
      gload16(A + (m0 + h*128 + srow + is*8)*NE + col,
              &As[(st & 1)*16384 + h*8192 + (wv*2 + is)*512]);
  };
  auto stageB = [&](int st, int h){
    if (st >= NKT) return;
    const long col = (long)st*64 + scol;
    #pragma unroll
    for (int is = 0; is < 2; ++is)
      gload16(Bw + (long)(n0 + h*128 + srow + is*8)*NE + col,
              &Bs[(st & 1)*16384 + h*8192 + (wv*2 + is)*512]);
  };

  auto lda = [&](int buf, int mi, int ks)->bf16x8 {
    const int row = wr*128 + mi*16 + l15;
    const int col = (ks*32 + lhi*8) ^ swz8;
    return *(const bf16x8*)&As[buf*16384 + row*64 + col];
  };
  auto ldb = [&](int buf, int ni, int ks)->bf16x8 {
    const int row = wc*64 + ni*16 + l15;
    const int col = (ks*32 + lhi*8) ^ swz8;
    return *(const bf16x8*)&Bs[buf*16384 + row*64 + col];
  };

  f32x4 acc[8][4];
  #pragma unroll
  for (int i=0;i<8;++i)
    #pragma unroll
    for (int j=0;j<4;++j)
      acc[i][j] = (f32x4){0.f,0.f,0.f,0.f};

  stageA(0,0); stageA(0,1); stageB(0,0); stageB(0,1);
  stageA(1,0); stageA(1,1); stageB(1,0); stageB(1,1);
  asm volatile("s_waitcnt vmcnt(8)" ::: "memory");
  __builtin_amdgcn_s_barrier();

  bf16x8 a0[4][2], a1[4][2], b0[2][2], b1[2][2];

  #pragma unroll 2
  for (int kt = 0; kt < NKT; ++kt){
    const int buf = kt & 1;

    // ---- phase 0: read A(qm0)+B(qn0); MFMA quad (qm0,qn0)
    #pragma unroll
    for (int i=0;i<4;++i){ a0[i][0]=lda(buf,i,0); a0[i][1]=lda(buf,i,1); }
    #pragma unroll
    for (int j=0;j<2;++j){ b0[j][0]=ldb(buf,j,0); b0[j][1]=ldb(buf,j,1); }
    __builtin_amdgcn_s_setprio(1);
    #pragma unroll
    for (int ks=0;ks<2;++ks)
      #pragma unroll
      for (int i=0;i<4;++i)
        #pragma unroll
        for (int j=0;j<2;++j)
          acc[i][j] = __builtin_amdgcn_mfma_f32_16x16x32_bf16(a0[i][ks], b0[j][ks], acc[i][j], 0,0,0);
    __builtin_amdgcn_s_setprio(0);
    __builtin_amdgcn_s_barrier();

    // ---- phase 1: read A(qm1); MFMA quad (qm1,qn0)   [last A-read of buf]
    #pragma unroll
    for (int i=0;i<4;++i){ a1[i][0]=lda(buf,4+i,0); a1[i][1]=lda(buf,4+i,1); }
    __builtin_amdgcn_s_setprio(1);
    #pragma unroll
    for (int ks=0;ks<2;++ks)
      #pragma unroll
      for (int i=0;i<4;++i)
        #pragma unroll
        for (int j=0;j<2;++j)
          acc[4+i][j] = __builtin_amdgcn_mfma_f32_16x16x32_bf16(a1[i][ks], b0[j][ks], acc[4+i][j], 0,0,0);
    __builtin_amdgcn_s_setprio(0);
    __builtin_amdgcn_s_barrier();

    // ---- phase 2: read B(qn1) [last B-read]; stage A(kt+2); MFMA (qm1,qn1)
    #pragma unroll
    for (int j=0;j<2;++j){ b1[j][0]=ldb(buf,2+j,0); b1[j][1]=ldb(buf,2+j,1); }
    stageA(kt+2, 0); stageA(kt+2, 1);
    __builtin_amdgcn_sched_barrier(0);
    __builtin_amdgcn_s_setprio(1);
    #pragma unroll
    for (int ks=0;ks<2;++ks)
      #pragma unroll
      for (int i=0;i<4;++i)
        #pragma unroll
        for (int j=0;j<2;++j)
          acc[4+i][2+j] = __builtin_amdgcn_mfma_f32_16x16x32_bf16(a1[i][ks], b1[j][ks], acc[4+i][2+j], 0,0,0);
    __builtin_amdgcn_s_setprio(0);
    __builtin_amdgcn_s_barrier();

    // ---- phase 3: stage B(kt+2); MFMA quad (qm0,qn1); counted vmcnt
    stageB(kt+2, 0); stageB(kt+2, 1);
    __builtin_amdgcn_sched_barrier(0);
    __builtin_amdgcn_s_setprio(1);
    #pragma unroll
    for (int ks=0;ks<2;++ks)
      #pragma unroll
      for (int i=0;i<4;++i)
        #pragma unroll
        for (int j=0;j<2;++j)
          acc[i][2+j] = __builtin_amdgcn_mfma_f32_16x16x32_bf16(a0[i][ks], b1[j][ks], acc[i][2+j], 0,0,0);
    __builtin_amdgcn_s_setprio(0);
    if (kt < NKT-2)       asm volatile("s_waitcnt vmcnt(8)" ::: "memory");
    else if (kt == NKT-2) asm volatile("s_waitcnt vmcnt(0)" ::: "memory");
    __builtin_amdgcn_s_barrier();
  }

  #pragma unroll
  for (int mi=0;mi<8;++mi){
    #pragma unroll
    for (int r=0;r<4;++r){
      const long mg = m0 + wr*128 + mi*16 + lhi*4 + r;
      const bool mz = (mode==1 || mode==2) ? (mask[mg] != 0) : false;
      #pragma unroll
      for (int ni=0;ni<4;++ni){
        const int ng = n0 + wc*64 + ni*16 + l15;
        float v = acc[mi][ni][r];
        if (mode==1) v = (v > 0.f) ? (v + 1.f) : __expf(v);
        if (mz) v = 0.f;
        if (mode==3) OF[mg*NE + ng] = v;
        else         Obf[mg*NE + ng] = f2bf(v);
      }
    }
  }
}

// ============ Q-projection GEMM with fused linear-attention epilogue ============
__global__ __launch_bounds__(512, 2) void gemm_q_attn(
    const unsigned short* __restrict__ A,
    const unsigned short* __restrict__ Wq,
    const unsigned short* __restrict__ KVfrag,
    unsigned short* __restrict__ attnb)
{
  __shared__ __align__(16) unsigned short As[2*256*64];
  __shared__ __align__(16) unsigned short Bs[2*256*64];

  const int nwg = (int)gridDim.x;
  const int bx  = (int)blockIdx.x;
  const int swz = (bx & 7) * (nwg >> 3) + (bx >> 3);
  const long m0 = (long)(swz >> 2) * 256;
  const int  n0 = (swz & 3) * 256;

  const int tid = (int)threadIdx.x;
  const int l   = tid & 63;
  const int wv  = tid >> 6;
  const int wr  = wv >> 2;
  const int wc  = wv & 3;
  const int l15 = l & 15;
  const int lhi = l >> 4;
  const int swz8 = (l & 7) * 8;

  const int srow = wv*16 + (l >> 3);
  const int scol = ((l & 7) * 8) ^ ((l >> 3) << 3);

  auto stageA = [&](int st, int h){
    if (st >= NKT) return;
    const long col = (long)st*64 + scol;
    #pragma unroll
    for (int is = 0; is < 2; ++is)
      gload16(A + (m0 + h*128 + srow + is*8)*NE + col,
              &As[(st & 1)*16384 + h*8192 + (wv*2 + is)*512]);
  };
  auto stageB = [&](int st, int h){
    if (st >= NKT) return;
    const long col = (long)st*64 + scol;
    #pragma unroll
    for (int is = 0; is < 2; ++is)
      gload16(Wq + (long)(n0 + h*128 + srow + is*8)*NE + col,
              &Bs[(st & 1)*16384 + h*8192 + (wv*2 + is)*512]);
  };

  auto lda = [&](int buf, int mi, int ks)->bf16x8 {
    const int row = wr*128 + mi*16 + l15;
    const int col = (ks*32 + lhi*8) ^ swz8;
    return *(const bf16x8*)&As[buf*16384 + row*64 + col];
  };
  auto ldb = [&](int buf, int ni, int ks)->bf16x8 {
    const int row = wc*64 + ni*16 + l15;
    const int col = (ks*32 + lhi*8) ^ swz8;
    return *(const bf16x8*)&Bs[buf*16384 + row*64 + col];
  };

  f32x4 acc[8][4];
  #pragma unroll
  for (int i=0;i<8;++i)
    #pragma unroll
    for (int j=0;j<4;++j)
      acc[i][j] = (f32x4){0.f,0.f,0.f,0.f};

  stageA(0,0); stageA(0,1); stageB(0,0); stageB(0,1);
  stageA(1,0); stageA(1,1); stageB(1,0); stageB(1,1);
  asm volatile("s_waitcnt vmcnt(8)" ::: "memory");
  __builtin_amdgcn_s_barrier();

  bf16x8 a0[4][2], a1[4][2], b0[2][2], b1[2][2];

  #pragma unroll 2
  for (int kt = 0; kt < NKT; ++kt){
    const int buf = kt & 1;

    #pragma unroll
    for (int i=0;i<4;++i){ a0[i][0]=lda(buf,i,0); a0[i][1]=lda(buf,i,1); }
    #pragma unroll
    for (int j=0;j<2;++j){ b0[j][0]=ldb(buf,j,0); b0[j][1]=ldb(buf,j,1); }
    __builtin_amdgcn_s_setprio(1);
    #pragma unroll
    for (int ks=0;ks<2;++ks)
      #pragma unroll
      for (int i=0;i<4;++i)
        #pragma unroll
        for (int j=0;j<2;++j)
          acc[i][j] = __builtin_amdgcn_mfma_f32_16x16x32_bf16(a0[i][ks], b0[j][ks], acc[i][j], 0,0,0);
    __builtin_amdgcn_s_setprio(0);
    __builtin_amdgcn_s_barrier();

    #pragma unroll
    for (int i=0;i<4;++i){ a1[i][0]=lda(buf,4+i,0); a1[i][1]=lda(buf,4+i,1); }
    __builtin_amdgcn_s_setprio(1);
    #pragma unroll
    for (int ks=0;ks<2;++ks)
      #pragma unroll
      for (int i=0;i<4;++i)
        #pragma unroll
        for (int j=0;j<2;++j)
          acc[4+i][j] = __builtin_amdgcn_mfma_f32_16x16x32_bf16(a1[i][ks], b0[j][ks], acc[4+i][j], 0,0,0);
    __builtin_amdgcn_s_setprio(0);
    __builtin_amdgcn_s_barrier();

    #pragma unroll
    for (int j=0;j<2;++j){ b1[j][0]=ldb(buf,2+j,0); b1[j][1]=ldb(buf,2+j,1); }
    stageA(kt+2, 0); stageA(kt+2, 1);
    __builtin_amdgcn_sched_barrier(0);
    __builtin_amdgcn_s_setprio(1);
    #pragma unroll
    for (int ks=0;ks<2;++ks)
      #pragma unroll
      for (int i=0;i<4;++i)
        #pragma unroll
        for (int j=0;j<2;++j)
          acc[4+i][2+j] = __builtin_amdgcn_mfma_f32_16x16x32_bf16(a1[i][ks], b1[j][ks], acc[4+i][2+j], 0,0,0);
    __builtin_amdgcn_s_setprio(0);
    __builtin_amdgcn_s_barrier();

    stageB(kt+2, 0); stageB(kt+2, 1);
    __builtin_amdgcn_sched_barrier(0);
    __builtin_amdgcn_s_setprio(1);
    #pragma unroll
    for (int ks=0;ks<2;++ks)
      #pragma unroll
      for (int i=0;i<4;++i)
        #pragma unroll
        for (int j=0;j<2;++j)
          acc[i][2+j] = __builtin_amdgcn_mfma_f32_16x16x32_bf16(a0[i][ks], b1[j][ks], acc[i][2+j], 0,0,0);
    __builtin_amdgcn_s_setprio(0);
    if (kt < NKT-2)       asm volatile("s_waitcnt vmcnt(8)" ::: "memory");
    else if (kt == NKT-2) asm volatile("s_waitcnt vmcnt(0)" ::: "memory");
    __builtin_amdgcn_s_barrier();
  }

  // ---- fused attn epilogue (per-wave private; no cross-wave sync) ----
  const int b  = (int)(m0 >> 13);             // 8192 rows per batch
  const int h  = (swz & 3)*4 + wc;            // this wave's head
  const long bh = (long)(b*16 + h);
  unsigned short* pool = (wv < 4) ? &As[wv*8192] : &Bs[(wv-4)*8192];  // 128 rows x 64 shorts

  // q = elu(acc)+1 -> bf16 -> pool (row stride 128B, XOR-swizzled)
  #pragma unroll
  for (int mi=0;mi<8;++mi){
    #pragma unroll
    for (int r=0;r<4;++r){
      const int row = mi*16 + lhi*4 + r;
      #pragma unroll
      for (int ni=0;ni<4;++ni){
        float v = acc[mi][ni][r];
        v = (v > 0.f) ? (v + 1.f) : __expf(v);
        const int colb = (ni*16 + l15)*2;
        *(unsigned short*)((char*)pool + row*128 + (colb ^ ((row & 7) << 4))) = f2bf(v);
      }
    }
  }

  // this head's KV fragments: [ks 0..3][nt 0..4][lane][8]
  bf16x8 bfv[4][5];
  #pragma unroll
  for (int ks=0; ks<4; ++ks)
    #pragma unroll
    for (int nt=0; nt<5; ++nt)
      bfv[ks][nt] = *(const bf16x8*)(KVfrag + bh*10240 + (ks*5+nt)*512 + l*8);

  asm volatile("s_waitcnt lgkmcnt(0)" ::: "memory");
  __builtin_amdgcn_sched_barrier(0);

  const int swzb = (l15 & 7) << 4;
  #pragma unroll
  for (int rt=0; rt<8; ++rt){
    const int rb = (rt*16 + l15)*128;
    bf16x8 qa0 = *(const bf16x8*)((const char*)pool + rb + ((lhi*16) ^ swzb));
    bf16x8 qa1 = *(const bf16x8*)((const char*)pool + rb + ((64 + lhi*16) ^ swzb));
    f32x4 at[5];
    #pragma unroll
    for (int nt=0; nt<5; ++nt){
      at[nt] = (f32x4){0.f,0.f,0.f,0.f};
      at[nt] = __builtin_amdgcn_mfma_f32_16x16x32_bf16(qa0, bfv[0][nt], at[nt], 0,0,0);
      at[nt] = __builtin_amdgcn_mfma_f32_16x16x32_bf16(qa1, bfv[1][nt], at[nt], 0,0,0);
      at[nt] = __builtin_amdgcn_mfma_f32_16x16x32_bf16(qa0, bfv[2][nt], at[nt], 0,0,0);
      at[nt] = __builtin_amdgcn_mfma_f32_16x16x32_bf16(qa1, bfv[3][nt], at[nt], 0,0,0);
    }
    float dv[4];
    #pragma unroll
    for (int e=0;e<4;++e){
      float d = __shfl(at[4][e], l & 48, 64);
      dv[e] = 1.f / (d + 1e-6f);
    }
    // direct normalized store (4 x 32B segments per instr; attn is L3-resident
    // for the out-projection, so sub-128B segments are absorbed by L2/L3)
    #pragma unroll
    for (int e=0;e<4;++e){
      const long grow = m0 + wr*128 + rt*16 + lhi*4 + e;
      #pragma unroll
      for (int nt=0; nt<4; ++nt)
        attnb[grow*NE + h*ND + nt*16 + l15] = f2bf(at[nt][e] * dv[e]);
    }
  }
}

// ---- kv_reduce: partial[bh][chunk] = sum over 512 rows of K^T V (64x64) + Ksum ----
__global__ __launch_bounds__(256) void kv_reduce(const unsigned short* __restrict__ K,
                                                 const unsigned short* __restrict__ V,
                                                 float* __restrict__ part){
  __shared__ float lds[2*64*68 + 192];
  float* Ksf = lds;
  float* Vsf = lds + 64*68;
  float* kcorner = lds + 2*64*68;

  const int bid = blockIdx.x;
  const int bh = bid >> 4;        // 0..63
  const int chunk = bid & 15;     // 16 chunks of 512 rows
  const int b = bh >> 4, h = bh & 15;
  const int t = threadIdx.x, w = t >> 6, l = t & 63;
  const int dg = l & 7, eg = l >> 3;
  const int d0 = dg*8, e0 = eg*8;
  const long base = ((long)b*NS + (long)chunk*512)*NE + h*ND;

  f32x4 acc[8][2];
  #pragma unroll
  for (int j=0;j<8;++j){ acc[j][0]=(f32x4){0,0,0,0}; acc[j][1]=(f32x4){0,0,0,0}; }
  f32x4 ksa = (f32x4){0,0,0,0}, ksb = (f32x4){0,0,0,0};

  for (int sc = 0; sc < 8; ++sc){    // 8 tiles of 64 rows
    if (sc) __syncthreads();
    const long rbase = base + (long)sc*64*NE;
    #pragma unroll
    for (int p = 0; p < 2; ++p){
      const int g = p*256 + t;
      const int row = g >> 3, cg = (g & 7)*8;
      u16x8 ku = *(const u16x8*)(K + rbase + (long)row*NE + cg);
      u16x8 vu = *(const u16x8*)(V + rbase + (long)row*NE + cg);
      #pragma unroll
      for (int j=0;j<8;++j){
        Ksf[row*68 + cg + j] = bf2f(ku[j]);
        Vsf[row*68 + cg + j] = bf2f(vu[j]);
      }
    }
    __syncthreads();
    #pragma unroll 2
    for (int i = 0; i < 16; ++i){
      const int r = w*16 + i;
      f32x4 k0 = *(const f32x4*)&Ksf[r*68 + d0];
      f32x4 k1 = *(const f32x4*)&Ksf[r*68 + d0 + 4];
      f32x4 v0 = *(const f32x4*)&Vsf[r*68 + e0];
      f32x4 v1 = *(const f32x4*)&Vsf[r*68 + e0 + 4];
      #pragma unroll
      for (int j=0;j<4;++j){
        acc[j][0]   += k0[j]*v0;  acc[j][1]   += k0[j]*v1;
        acc[4+j][0] += k1[j]*v0;  acc[4+j][1] += k1[j]*v1;
      }
      if (eg == 0){ ksa += k0; ksb += k1; }
    }
  }

  __syncthreads();
  if (w >= 1 && eg == 0){
    *(f32x4*)&kcorner[(w-1)*64 + d0]     = ksa;
    *(f32x4*)&kcorner[(w-1)*64 + d0 + 4] = ksb;
  }
  if (w >= 2){
    float* reg = (w==2) ? Ksf : Vsf;
    #pragma unroll
    for (int j=0;j<8;++j)
      #pragma unroll
      for (int q=0;q<2;++q)
        *(f32x4*)&reg[l*68 + (j*2+q)*4] = acc[j][q];
  }
  __syncthreads();
  if (w < 2){
    float* reg = (w==0) ? Ksf : Vsf;
    #pragma unroll
    for (int j=0;j<8;++j)
      #pragma unroll
      for (int q=0;q<2;++q)
        acc[j][q] += *(const f32x4*)&reg[l*68 + (j*2+q)*4];
  }
  __syncthreads();
  if (w == 1){
    #pragma unroll
    for (int j=0;j<8;++j)
      #pragma unroll
      for (int q=0;q<2;++q)
        *(f32x4*)&Ksf[l*68 + (j*2+q)*4] = acc[j][q];
  }
  __syncthreads();
  if (w == 0){
    #pragma unroll
    for (int j=0;j<8;++j)
      #pragma unroll
      for (int q=0;q<2;++q)
        acc[j][q] += *(const f32x4*)&Ksf[l*68 + (j*2+q)*4];
    float* po = part + (long)(bh*16 + chunk)*4160;
    #pragma unroll
    for (int j=0;j<8;++j)
      #pragma unroll
      for (int q=0;q<2;++q)
        *(f32x4*)&po[(d0 + j)*64 + e0 + q*4] = acc[j][q];
    if (eg == 0){
      #pragma unroll
      for (int i=0;i<3;++i){
        ksa += *(const f32x4*)&kcorner[i*64 + d0];
        ksb += *(const f32x4*)&kcorner[i*64 + d0 + 4];
      }
      *(f32x4*)&po[4096 + d0]     = ksa;
      *(f32x4*)&po[4096 + d0 + 4] = ksb;
    }
  }
}

// ---- kv_finish: sum partials, emit KV' = [KV | Ksum] as hi/lo bf16 B-fragments ----
__global__ __launch_bounds__(256) void kv_finish(const float* __restrict__ part,
                                                 unsigned short* __restrict__ KVfrag){
  __shared__ float KVf[64*65 + 32];
  const int bh = blockIdx.x, t = threadIdx.x;
  const float* pb = part + (long)bh*16*4160;

  #pragma unroll
  for (int p = 0; p < 4; ++p){
    int g = p*256 + t;
    f32x4 s = (f32x4){0.f,0.f,0.f,0.f};
    for (int c = 0; c < 16; ++c) s += *(const f32x4*)&pb[c*4160 + g*4];
    int d = g >> 4, e = (g & 15)*4;
    KVf[d*65 + e+0] = s[0];
    KVf[d*65 + e+1] = s[1];
    KVf[d*65 + e+2] = s[2];
    KVf[d*65 + e+3] = s[3];
  }
  if (t < 16){
    f32x4 s = (f32x4){0.f,0.f,0.f,0.f};
    for (int c = 0; c < 16; ++c) s += *(const f32x4*)&pb[c*4160 + 4096 + t*4];
    #pragma unroll
    for (int j=0;j<4;++j) KVf[(t*4+j)*65 + 64] = s[j];
  }
  __syncthreads();

  for (int idx = t; idx < 10240; idx += 256){
    int j   = idx & 7;
    int lfr = (idx >> 3) & 63;
    int grp = idx >> 9;
    int nt  = grp % 5, ks = grp / 5;
    int kk  = (ks & 1)*32 + (lfr >> 4)*8 + j;
    int n   = nt*16 + (lfr & 15);
    float v = (n <= 64) ? KVf[kk*65 + n] : 0.f;
    unsigned short hi = f2bf(v);
    unsigned short o  = (ks >> 1) ? f2bf(v - bf2f(hi)) : hi;
    KVfrag[(long)bh*10240 + idx] = o;
  }
}

extern "C" void kernel_launch(void* const* d_in, const int* in_sizes, int n_in,
                              void* d_out, int out_size, void* d_ws, size_t ws_size,
                              hipStream_t stream){
  (void)in_sizes; (void)n_in; (void)out_size; (void)ws_size;
  const float* x    = (const float*)d_in[0];
  const void*  mraw = d_in[1];
  const float* Wq   = (const float*)d_in[2];
  const float* Wk   = (const float*)d_in[3];
  const float* Wv   = (const float*)d_in[4];
  const float* Wo   = (const float*)d_in[5];
  float* out = (float*)d_out;
  char* ws = (char*)d_ws;

  unsigned short* xb  = (unsigned short*)(ws + 0L);           // 64 MB bf16 x (lives until q_attn)
  unsigned short* Wqb = (unsigned short*)(ws + 67108864L);
  unsigned short* Wkb = (unsigned short*)(ws + 69206016L);
  unsigned short* Wvb = (unsigned short*)(ws + 71303168L);
  unsigned short* Wob = (unsigned short*)(ws + 73400320L);
  unsigned short* Qb  = (unsigned short*)(ws + 75497472L);    // 64 MB: kv partials, then attn
  unsigned short* Kb  = (unsigned short*)(ws + 142606336L);
  unsigned short* Vb  = (unsigned short*)(ws + 209715200L);
  unsigned short* KVfrag = (unsigned short*)(ws + 276824064L);
  unsigned char* mask_u8 = (unsigned char*)(ws + 278462464L);
  float* part = (float*)Qb;               // 17 MB partials (consumed by kv_finish
  unsigned short* attnb = Qb;             // before q_attn overwrites with attn)

  CastJobs J;
  J.src[0]=x;  J.dst[0]=xb;  J.n4[0]=NM*NE/4;
  J.src[1]=Wq; J.dst[1]=Wqb; J.n4[1]=NE*NE/4;
  J.src[2]=Wk; J.dst[2]=Wkb; J.n4[2]=NE*NE/4;
  J.src[3]=Wv; J.dst[3]=Wvb; J.n4[3]=NE*NE/4;
  J.src[4]=Wo; J.dst[4]=Wob; J.n4[4]=NE*NE/4;
  castk<<<dim3(2048,6), 256, 0, stream>>>(J, mraw, mask_u8);

  // K,V projections
  gemm256<<<dim3(512,2), 512, 0, stream>>>(xb, Wkb, Wvb, Kb, Vb, nullptr, mask_u8, -1);

  kv_reduce<<<dim3(1024), 256, 0, stream>>>(Kb, Vb, part);
  kv_finish<<<dim3(64), 256, 0, stream>>>(part, KVfrag);

  // Q projection + fused attn (writes attn into Qb region)
  gemm_q_attn<<<dim3(512), 512, 0, stream>>>(xb, Wqb, KVfrag, attnb);

  // final projection: out = attn @ Wo^T (f32 out)
  gemm256<<<dim3(512,1), 512, 0, stream>>>(attnb, Wob, Wob, nullptr, nullptr, out, mask_u8, 3);
}